// Round 7
// baseline (101.851 us; speedup 1.0000x reference)
//
#include <hip/hip_runtime.h>
#include <stdint.h>

#define B_ 64
#define T_ 256
#define DF 32
#define L_ 128
#define AW 34      // solve-matrix row stride in floats
#define SLICE 4352 // per-wave LDS slice: As = 32*34*4 bytes

typedef float f32x16 __attribute__((ext_vector_type(16)));
typedef short bf16x8 __attribute__((ext_vector_type(8)));

// wave-private barrier: drain LDS ops; sched_barrier stops hoisting (rule #18)
#define WAVE_SYNC() do { asm volatile("s_waitcnt lgkmcnt(0)" ::: "memory"); \
                         __builtin_amdgcn_sched_barrier(0); } while (0)

__device__ __forceinline__ float readlane_f(float v, int l) {
    return __builtin_bit_cast(float, __builtin_amdgcn_readlane(__builtin_bit_cast(int, v), l));
}
__device__ __forceinline__ uint32_t cvt_pk_bf16(float a, float b) {
    uint32_t r;
    asm("v_cvt_pk_bf16_f32 %0, %1, %2" : "=v"(r) : "v"(a), "v"(b));
    return r;   // lo16 = bf16(a), hi16 = bf16(b)
}
__device__ __forceinline__ float lo_f(uint32_t p) { return __builtin_bit_cast(float, p << 16); }
__device__ __forceinline__ float hi_f(uint32_t p) { return __builtin_bit_cast(float, p & 0xFFFF0000u); }

struct frag3 { bf16x8 h, m, l; };
union U8 { uint32_t u[4]; bf16x8 v; };

// 3-way bf16 split of 8 f32 values (two float4): f = h + m + l, residual ~2^-27
__device__ __forceinline__ frag3 split3(float4 a, float4 b) {
    uint32_t h0 = cvt_pk_bf16(a.x, a.y), h1 = cvt_pk_bf16(a.z, a.w);
    uint32_t h2 = cvt_pk_bf16(b.x, b.y), h3 = cvt_pk_bf16(b.z, b.w);
    float e0 = a.x - lo_f(h0), e1 = a.y - hi_f(h0);
    float e2 = a.z - lo_f(h1), e3 = a.w - hi_f(h1);
    float e4 = b.x - lo_f(h2), e5 = b.y - hi_f(h2);
    float e6 = b.z - lo_f(h3), e7 = b.w - hi_f(h3);
    uint32_t m0 = cvt_pk_bf16(e0, e1), m1 = cvt_pk_bf16(e2, e3);
    uint32_t m2 = cvt_pk_bf16(e4, e5), m3 = cvt_pk_bf16(e6, e7);
    float g0 = e0 - lo_f(m0), g1 = e1 - hi_f(m0);
    float g2 = e2 - lo_f(m1), g3 = e3 - hi_f(m1);
    float g4 = e4 - lo_f(m2), g5 = e5 - hi_f(m2);
    float g6 = e6 - lo_f(m3), g7 = e7 - hi_f(m3);
    uint32_t l0 = cvt_pk_bf16(g0, g1), l1 = cvt_pk_bf16(g2, g3);
    uint32_t l2 = cvt_pk_bf16(g4, g5), l3 = cvt_pk_bf16(g6, g7);
    U8 H, M, L;
    H.u[0] = h0; H.u[1] = h1; H.u[2] = h2; H.u[3] = h3;
    M.u[0] = m0; M.u[1] = m1; M.u[2] = m2; M.u[3] = m3;
    L.u[0] = l0; L.u[1] = l1; L.u[2] = l2; L.u[3] = l3;
    frag3 r; r.h = H.v; r.m = M.v; r.l = L.v; return r;
}

__device__ __forceinline__ f32x16 mfma32(bf16x8 a, bf16x8 b, f32x16 c) {
    return __builtin_amdgcn_mfma_f32_32x32x16_bf16(a, b, c, 0, 0, 0);
}

// One wave per (b,t) token; 4 independent waves per 256-thread block.
__global__ __launch_bounds__(256, 2) void feat_kernel(
    const float* __restrict__ x,       // [B,T,32]
    const float* __restrict__ latent,  // [B,T,128]
    const float* __restrict__ kern,    // [32,128]
    const float* __restrict__ bias,    // [32,128]
    const float* __restrict__ beta,    // [T]
    float* __restrict__ out,           // mode0: ws[B,T,128] ; mode1: out[B,128]
    int mode)
{
    __shared__ __align__(16) char smem[4 * SLICE];
    const int tid  = threadIdx.x;
    const int wid  = tid >> 6;
    const int lane = tid & 63;
    const int bt   = blockIdx.x * 4 + wid;

    float* As = reinterpret_cast<float*>(smem + wid * SLICE);

    const int g  = lane >> 5;   // k-group (also wave half)
    const int r  = lane & 31;   // my feature row / solve row / o_hat column

    const float4* kern4 = reinterpret_cast<const float4*>(kern);
    const float4* bias4 = reinterpret_cast<const float4*>(bias);
    const float4* lat4  = reinterpret_cast<const float4*>(latent) + (size_t)bt * 32;
    const float*  xp    = x + (size_t)bt * DF;

    const float xr = xp[r];     // x[r] in lane r (mirrored across halves)

    f32x16 G;
    #pragma unroll
    for (int i = 0; i < 16; ++i) G[i] = 0.f;
    float ay = 0.f;

    // ---- 8 k-steps of 16: build row-frag, MFMA Gram (3-split, 6 products), VALU xty ----
    #pragma unroll 4
    for (int ks = 0; ks < 8; ++ks) {
        const int idx = r * 32 + ks * 4 + g * 2;   // float4 index; k = ks*16 + g*8
        float4 Ka = kern4[idx],     Kb = kern4[idx + 1];
        float4 Ba = bias4[idx],     Bb = bias4[idx + 1];
        float4 fa, fb;
        fa.x = fmaxf(fmaf(xr, Ka.x, Ba.x), 0.f);
        fa.y = fmaxf(fmaf(xr, Ka.y, Ba.y), 0.f);
        fa.z = fmaxf(fmaf(xr, Ka.z, Ba.z), 0.f);
        fa.w = fmaxf(fmaf(xr, Ka.w, Ba.w), 0.f);
        fb.x = fmaxf(fmaf(xr, Kb.x, Bb.x), 0.f);
        fb.y = fmaxf(fmaf(xr, Kb.y, Bb.y), 0.f);
        fb.z = fmaxf(fmaf(xr, Kb.z, Bb.z), 0.f);
        fb.w = fmaxf(fmaf(xr, Kb.w, Bb.w), 0.f);

        // xty partial in f32 (exact path)
        float4 la = lat4[ks * 4 + g * 2], lb = lat4[ks * 4 + g * 2 + 1];
        ay = fmaf(fa.x, la.x, ay); ay = fmaf(fa.y, la.y, ay);
        ay = fmaf(fa.z, la.z, ay); ay = fmaf(fa.w, la.w, ay);
        ay = fmaf(fb.x, lb.x, ay); ay = fmaf(fb.y, lb.y, ay);
        ay = fmaf(fb.z, lb.z, ay); ay = fmaf(fb.w, lb.w, ay);

        frag3 F = split3(fa, fb);
        // G += F F^T : hh + hm + mh + hl + lh + mm (single chain, pipe-rate accumulate)
        G = mfma32(F.h, F.h, G);
        G = mfma32(F.h, F.m, G);
        G = mfma32(F.m, F.h, G);
        G = mfma32(F.h, F.l, G);
        G = mfma32(F.l, F.h, G);
        G = mfma32(F.m, F.m, G);
    }
    ay += __shfl_xor(ay, 32);   // combine the two k-halves -> full xty[r] in every lane

    // ---- spill G + xty into per-wave LDS solve matrix ----
    #pragma unroll
    for (int reg = 0; reg < 16; ++reg) {
        const int row = (reg & 3) + 8 * (reg >> 2) + 4 * g;  // m101 C-layout
        As[row * AW + r] = G[reg];
    }
    if (g == 0) As[r * AW + 32] = ay;
    WAVE_SYNC();

    // ---- pull my row into registers (lanes 32..63 mirror rows 0..31) ----
    float A[33];
    #pragma unroll
    for (int jj = 0; jj < 16; ++jj) {
        A[2 * jj]     = As[r * AW + 2 * jj];
        A[2 * jj + 1] = As[r * AW + 2 * jj + 1];
    }
    A[32] = As[r * AW + 32];

    // ---- register Gauss-Jordan (SPD, no pivot), fully unrolled, no barriers ----
    float dinv = 0.f;
    #pragma unroll
    for (int k = 0; k < 32; ++k) {
        float piv = readlane_f(A[k], k);
        float ip = __builtin_amdgcn_rcpf(piv);
        ip = ip * (2.0f - piv * ip);               // Newton refine
        const bool isk = (r == k);
        float fmul = isk ? 0.f : A[k] * ip;        // pivot row doesn't update
        dinv = isk ? ip : dinv;                    // capture my diagonal reciprocal
        #pragma unroll
        for (int j = k + 1; j <= 32; ++j) {
            float pkj = readlane_f(A[j], k);
            A[j] = fmaf(-fmul, pkj, A[j]);
        }
    }
    const float s = A[32] * dinv;   // my row's solution (mirrored across halves)

    // ---- o_hat: recompute F on the fly, f4-col = r, d split across halves ----
    {
        float4 o = make_float4(0.f, 0.f, 0.f, 0.f);
        #pragma unroll
        for (int dd = 0; dd < 16; ++dd) {
            int d = g * 16 + dd;
            float4 K  = kern4[d * 32 + r];
            float4 Bv = bias4[d * 32 + r];
            float xv = __shfl(xr, d);   // x[d] from lane d
            float sd = __shfl(s,  d);   // s[d] from lane d
            float fx = fmaxf(fmaf(xv, K.x, Bv.x), 0.f);
            float fy = fmaxf(fmaf(xv, K.y, Bv.y), 0.f);
            float fz = fmaxf(fmaf(xv, K.z, Bv.z), 0.f);
            float fw = fmaxf(fmaf(xv, K.w, Bv.w), 0.f);
            o.x = fmaf(sd, fx, o.x);
            o.y = fmaf(sd, fy, o.y);
            o.z = fmaf(sd, fz, o.z);
            o.w = fmaf(sd, fw, o.w);
        }
        o.x += __shfl_down(o.x, 32);
        o.y += __shfl_down(o.y, 32);
        o.z += __shfl_down(o.z, 32);
        o.w += __shfl_down(o.w, 32);

        if (mode == 0) {
            if (g == 0)
                reinterpret_cast<float4*>(out)[(size_t)bt * 32 + r] = o;
        } else {
            const int t = bt & (T_ - 1);
            float v = fabsf(beta[lane]) + fabsf(beta[lane + 64]) +
                      fabsf(beta[lane + 128]) + fabsf(beta[lane + 192]);
            #pragma unroll
            for (int off = 32; off > 0; off >>= 1) v += __shfl_down(v, off);
            float S = __shfl(v, 0);
            float w_t = fabsf(beta[t]) / S;
            if (g == 0) {
                float* op = &out[(size_t)(bt >> 8) * L_ + 4 * r];
                atomicAdd(op + 0, o.x * w_t);
                atomicAdd(op + 1, o.y * w_t);
                atomicAdd(op + 2, o.z * w_t);
                atomicAdd(op + 3, o.w * w_t);
            }
        }
    }
}

__global__ __launch_bounds__(256) void reduce_kernel(
    const float* __restrict__ ws,     // [B,T,128] o_hat (unscaled)
    const float* __restrict__ beta,   // [T]
    float* __restrict__ out)          // [B,128]
{
    __shared__ float wsh[T_];
    __shared__ __align__(16) float4 par[8][32];
    __shared__ float red[4];
    const int b = blockIdx.x, tid = threadIdx.x;

    float bv = fabsf(beta[tid]);
    wsh[tid] = bv;
    float v = bv;
    #pragma unroll
    for (int o = 32; o > 0; o >>= 1) v += __shfl_down(v, o);
    if ((tid & 63) == 0) red[tid >> 6] = v;
    __syncthreads();
    const float S = red[0] + red[1] + red[2] + red[3];

    const int c = tid & 31, gg = tid >> 5;
    const float4* ws4 = reinterpret_cast<const float4*>(ws);
    float4 a = make_float4(0.f, 0.f, 0.f, 0.f);
    #pragma unroll 4
    for (int tt = 0; tt < 32; ++tt) {
        int t = gg * 32 + tt;
        float w = wsh[t];
        float4 u = ws4[((size_t)b * T_ + t) * 32 + c];
        a.x = fmaf(u.x, w, a.x);
        a.y = fmaf(u.y, w, a.y);
        a.z = fmaf(u.z, w, a.z);
        a.w = fmaf(u.w, w, a.w);
    }
    par[gg][c] = a;
    __syncthreads();
    if (tid < 32) {
        float4 s = par[0][tid];
        #pragma unroll
        for (int p = 1; p < 8; ++p) {
            float4 u = par[p][tid];
            s.x += u.x; s.y += u.y; s.z += u.z; s.w += u.w;
        }
        float inv = 1.0f / S;
        s.x *= inv; s.y *= inv; s.z *= inv; s.w *= inv;
        reinterpret_cast<float4*>(out)[b * 32 + tid] = s;
    }
}

extern "C" void kernel_launch(void* const* d_in, const int* in_sizes, int n_in,
                              void* d_out, int out_size, void* d_ws, size_t ws_size,
                              hipStream_t stream) {
    const float* x      = (const float*)d_in[0];
    const float* latent = (const float*)d_in[1];
    const float* kern   = (const float*)d_in[2];
    const float* bias   = (const float*)d_in[3];
    const float* beta   = (const float*)d_in[4];
    float* out = (float*)d_out;

    const size_t need = (size_t)B_ * T_ * L_ * sizeof(float);
    if (ws_size >= need) {
        float* ws = (float*)d_ws;
        feat_kernel<<<(B_ * T_) / 4, 256, 0, stream>>>(x, latent, kern, bias, beta, ws, 0);
        reduce_kernel<<<B_, 256, 0, stream>>>(ws, beta, out);
    } else {
        (void)hipMemsetAsync(d_out, 0, (size_t)out_size * sizeof(float), stream);
        feat_kernel<<<(B_ * T_) / 4, 256, 0, stream>>>(x, latent, kern, bias, beta, out, 1);
    }
}

// Round 8
// 94.223 us; speedup vs baseline: 1.0810x; 1.0810x over previous
//
#include <hip/hip_runtime.h>
#include <stdint.h>

#define B_ 64
#define T_ 256
#define DF 32
#define L_ 128
#define AW 34      // solve-matrix row stride in floats

typedef float f32x16 __attribute__((ext_vector_type(16)));
typedef short bf16x8 __attribute__((ext_vector_type(8)));

// wave-private barrier: drain LDS ops; sched_barrier stops hoisting (rule #18)
#define WAVE_SYNC() do { asm volatile("s_waitcnt lgkmcnt(0)" ::: "memory"); \
                         __builtin_amdgcn_sched_barrier(0); } while (0)

__device__ __forceinline__ float readlane_f(float v, int l) {
    return __builtin_bit_cast(float, __builtin_amdgcn_readlane(__builtin_bit_cast(int, v), l));
}
__device__ __forceinline__ uint32_t cvt_pk_bf16(float a, float b) {
    uint32_t r;
    asm("v_cvt_pk_bf16_f32 %0, %1, %2" : "=v"(r) : "v"(a), "v"(b));
    return r;   // lo16 = bf16(a), hi16 = bf16(b)
}
__device__ __forceinline__ float lo_f(uint32_t p) { return __builtin_bit_cast(float, p << 16); }
__device__ __forceinline__ float hi_f(uint32_t p) { return __builtin_bit_cast(float, p & 0xFFFF0000u); }

struct frag3 { bf16x8 h, m, l; };
union U8 { uint32_t u[4]; bf16x8 v; };

// 3-way bf16 split of 8 f32 values: f = h + m + l, residual ~2^-27
__device__ __forceinline__ frag3 split3(float4 a, float4 b) {
    uint32_t h0 = cvt_pk_bf16(a.x, a.y), h1 = cvt_pk_bf16(a.z, a.w);
    uint32_t h2 = cvt_pk_bf16(b.x, b.y), h3 = cvt_pk_bf16(b.z, b.w);
    float e0 = a.x - lo_f(h0), e1 = a.y - hi_f(h0);
    float e2 = a.z - lo_f(h1), e3 = a.w - hi_f(h1);
    float e4 = b.x - lo_f(h2), e5 = b.y - hi_f(h2);
    float e6 = b.z - lo_f(h3), e7 = b.w - hi_f(h3);
    uint32_t m0 = cvt_pk_bf16(e0, e1), m1 = cvt_pk_bf16(e2, e3);
    uint32_t m2 = cvt_pk_bf16(e4, e5), m3 = cvt_pk_bf16(e6, e7);
    float g0 = e0 - lo_f(m0), g1 = e1 - hi_f(m0);
    float g2 = e2 - lo_f(m1), g3 = e3 - hi_f(m1);
    float g4 = e4 - lo_f(m2), g5 = e5 - hi_f(m2);
    float g6 = e6 - lo_f(m3), g7 = e7 - hi_f(m3);
    uint32_t l0 = cvt_pk_bf16(g0, g1), l1 = cvt_pk_bf16(g2, g3);
    uint32_t l2 = cvt_pk_bf16(g4, g5), l3 = cvt_pk_bf16(g6, g7);
    U8 H, M, L;
    H.u[0] = h0; H.u[1] = h1; H.u[2] = h2; H.u[3] = h3;
    M.u[0] = m0; M.u[1] = m1; M.u[2] = m2; M.u[3] = m3;
    L.u[0] = l0; L.u[1] = l1; L.u[2] = l2; L.u[3] = l3;
    frag3 r; r.h = H.v; r.m = M.v; r.l = L.v; return r;
}

__device__ __forceinline__ f32x16 mfma32(bf16x8 a, bf16x8 b, f32x16 c) {
    return __builtin_amdgcn_mfma_f32_32x32x16_bf16(a, b, c, 0, 0, 0);
}

// ---- Gauss-Jordan round K, column-interleaved register layout ----
// lane g*32+r holds row r, cols {2m+g} in A[0..16]. One fma updates 2 cols.
template <int K>
__device__ __forceinline__ void gj_round(float (&A)[17], float& dinv, int r, int g) {
    constexpr int HK = K & 1;          // half owning column K
    constexpr int MK = (K - HK) >> 1;  // register slot of column K
    float piv = readlane_f(A[MK], HK * 32 + K);      // A[K][K]
    float ip = __builtin_amdgcn_rcpf(piv);
    ip = ip * (2.0f - piv * ip);                     // Newton refine
    float other = __shfl_xor(A[MK], 32);             // pair lane's col-K slot
    float akr = (g == HK) ? A[MK] : other;           // my row's col-K value
    const bool isk = (r == K);
    float fmul = isk ? 0.f : akr * ip;
    dinv = isk ? ip : dinv;
    #pragma unroll
    for (int m = (K >> 1); m < 17; ++m) {
        // pk = row K's value of MY column (2m+g): lane g*32+K via per-group bcast
        float pk = __builtin_bit_cast(float, __builtin_amdgcn_ds_swizzle(
                       __builtin_bit_cast(int, A[m]), (K << 5)));
        A[m] = fmaf(-fmul, pk, A[m]);
    }
}

template <int K>
struct GJ {
    static __device__ __forceinline__ void run(float (&A)[17], float& dinv, int r, int g) {
        gj_round<K>(A, dinv, r, g);
        GJ<K + 1>::run(A, dinv, r, g);
    }
};
template <>
struct GJ<32> {
    static __device__ __forceinline__ void run(float (&)[17], float&, int, int) {}
};

// One wave (64 threads) per (b,t) token.
__global__ __launch_bounds__(64) void feat_kernel(
    const float* __restrict__ x,       // [B,T,32]
    const float* __restrict__ latent,  // [B,T,128]
    const float* __restrict__ kern,    // [32,128]
    const float* __restrict__ bias,    // [32,128]
    const float* __restrict__ beta,    // [T]
    float* __restrict__ out,           // mode0: ws[B,T,128] ; mode1: out[B,128]
    int mode)
{
    __shared__ float As[DF * AW];      // 4352 B
    const int lane = threadIdx.x;
    const int bt   = blockIdx.x;

    const int g = lane >> 5;   // half (k-group / column-parity owner)
    const int r = lane & 31;   // my feature row / solve row / o_hat column

    const float4* kern4 = reinterpret_cast<const float4*>(kern);
    const float4* bias4 = reinterpret_cast<const float4*>(bias);
    const float4* lat4  = reinterpret_cast<const float4*>(latent) + (size_t)bt * 32;
    const float*  xp    = x + (size_t)bt * DF;

    const float xr = xp[r];     // x[r] in lane r (mirrored across halves)

    f32x16 G;
    #pragma unroll
    for (int i = 0; i < 16; ++i) G[i] = 0.f;
    float ay = 0.f;

    // ---- 8 k-steps of 16: build row-frag, MFMA Gram (3-split, 6 products), VALU xty ----
    #pragma unroll 2
    for (int ks = 0; ks < 8; ++ks) {
        const int idx = r * 32 + ks * 4 + g * 2;   // float4 index; k = ks*16 + g*8
        float4 Ka = kern4[idx],     Kb = kern4[idx + 1];
        float4 Ba = bias4[idx],     Bb = bias4[idx + 1];
        float4 fa, fb;
        fa.x = fmaxf(fmaf(xr, Ka.x, Ba.x), 0.f);
        fa.y = fmaxf(fmaf(xr, Ka.y, Ba.y), 0.f);
        fa.z = fmaxf(fmaf(xr, Ka.z, Ba.z), 0.f);
        fa.w = fmaxf(fmaf(xr, Ka.w, Ba.w), 0.f);
        fb.x = fmaxf(fmaf(xr, Kb.x, Bb.x), 0.f);
        fb.y = fmaxf(fmaf(xr, Kb.y, Bb.y), 0.f);
        fb.z = fmaxf(fmaf(xr, Kb.z, Bb.z), 0.f);
        fb.w = fmaxf(fmaf(xr, Kb.w, Bb.w), 0.f);

        // xty partial in f32 (exact path)
        float4 la = lat4[ks * 4 + g * 2], lb = lat4[ks * 4 + g * 2 + 1];
        ay = fmaf(fa.x, la.x, ay); ay = fmaf(fa.y, la.y, ay);
        ay = fmaf(fa.z, la.z, ay); ay = fmaf(fa.w, la.w, ay);
        ay = fmaf(fb.x, lb.x, ay); ay = fmaf(fb.y, lb.y, ay);
        ay = fmaf(fb.z, lb.z, ay); ay = fmaf(fb.w, lb.w, ay);

        frag3 F = split3(fa, fb);
        // G += F F^T : hh + hm + mh + hl + lh + mm
        G = mfma32(F.h, F.h, G);
        G = mfma32(F.h, F.m, G);
        G = mfma32(F.m, F.h, G);
        G = mfma32(F.h, F.l, G);
        G = mfma32(F.l, F.h, G);
        G = mfma32(F.m, F.m, G);
    }
    ay += __shfl_xor(ay, 32);   // combine k-halves -> full xty[r] in every lane

    // ---- spill G + xty into LDS solve matrix (row-major) ----
    #pragma unroll
    for (int reg = 0; reg < 16; ++reg) {
        const int row = (reg & 3) + 8 * (reg >> 2) + 4 * g;  // m101 C-layout
        As[row * AW + r] = G[reg];
    }
    if (g == 0) As[r * AW + 32] = ay;
    WAVE_SYNC();

    // ---- reload column-interleaved: lane g*32+r <- row r, cols {2m+g} ----
    float A[17];
    #pragma unroll
    for (int m = 0; m < 17; ++m) A[m] = As[r * AW + 2 * m + g];
    // (g=1,m=16 reads col 33: in-bounds pad, dead value)

    // ---- register Gauss-Jordan, 2-cols-per-instruction, no barriers ----
    float dinv = 0.f;
    GJ<0>::run(A, dinv, r, g);
    const float s = A[16] * dinv;   // col 32 lives in half 0 (g==0)

    // ---- o_hat: recompute F on the fly, f4-col = r, d split across halves ----
    {
        float4 o = make_float4(0.f, 0.f, 0.f, 0.f);
        #pragma unroll
        for (int dd = 0; dd < 16; ++dd) {
            int d = g * 16 + dd;
            float4 K  = kern4[d * 32 + r];
            float4 Bv = bias4[d * 32 + r];
            float xv = __shfl(xr, d);   // x[d] from lane d
            float sd = __shfl(s,  d);   // s[d] from lane d (d<32: half 0, fresh)
            float fx = fmaxf(fmaf(xv, K.x, Bv.x), 0.f);
            float fy = fmaxf(fmaf(xv, K.y, Bv.y), 0.f);
            float fz = fmaxf(fmaf(xv, K.z, Bv.z), 0.f);
            float fw = fmaxf(fmaf(xv, K.w, Bv.w), 0.f);
            o.x = fmaf(sd, fx, o.x);
            o.y = fmaf(sd, fy, o.y);
            o.z = fmaf(sd, fz, o.z);
            o.w = fmaf(sd, fw, o.w);
        }
        o.x += __shfl_down(o.x, 32);
        o.y += __shfl_down(o.y, 32);
        o.z += __shfl_down(o.z, 32);
        o.w += __shfl_down(o.w, 32);

        if (mode == 0) {
            if (g == 0)
                reinterpret_cast<float4*>(out)[(size_t)bt * 32 + r] = o;
        } else {
            const int t = bt & (T_ - 1);
            float v = fabsf(beta[lane]) + fabsf(beta[lane + 64]) +
                      fabsf(beta[lane + 128]) + fabsf(beta[lane + 192]);
            #pragma unroll
            for (int off = 32; off > 0; off >>= 1) v += __shfl_down(v, off);
            float S = __shfl(v, 0);
            float w_t = fabsf(beta[t]) / S;
            if (g == 0) {
                float* op = &out[(size_t)(bt >> 8) * L_ + 4 * r];
                atomicAdd(op + 0, o.x * w_t);
                atomicAdd(op + 1, o.y * w_t);
                atomicAdd(op + 2, o.z * w_t);
                atomicAdd(op + 3, o.w * w_t);
            }
        }
    }
}

__global__ __launch_bounds__(256) void reduce_kernel(
    const float* __restrict__ ws,     // [B,T,128] o_hat (unscaled)
    const float* __restrict__ beta,   // [T]
    float* __restrict__ out)          // [B,128]
{
    __shared__ float wsh[T_];
    __shared__ __align__(16) float4 par[8][32];
    __shared__ float red[4];
    const int b = blockIdx.x, tid = threadIdx.x;

    float bv = fabsf(beta[tid]);
    wsh[tid] = bv;
    float v = bv;
    #pragma unroll
    for (int o = 32; o > 0; o >>= 1) v += __shfl_down(v, o);
    if ((tid & 63) == 0) red[tid >> 6] = v;
    __syncthreads();
    const float S = red[0] + red[1] + red[2] + red[3];

    const int c = tid & 31, gg = tid >> 5;
    const float4* ws4 = reinterpret_cast<const float4*>(ws);
    float4 a = make_float4(0.f, 0.f, 0.f, 0.f);
    #pragma unroll 4
    for (int tt = 0; tt < 32; ++tt) {
        int t = gg * 32 + tt;
        float w = wsh[t];
        float4 u = ws4[((size_t)b * T_ + t) * 32 + c];
        a.x = fmaf(u.x, w, a.x);
        a.y = fmaf(u.y, w, a.y);
        a.z = fmaf(u.z, w, a.z);
        a.w = fmaf(u.w, w, a.w);
    }
    par[gg][c] = a;
    __syncthreads();
    if (tid < 32) {
        float4 s = par[0][tid];
        #pragma unroll
        for (int p = 1; p < 8; ++p) {
            float4 u = par[p][tid];
            s.x += u.x; s.y += u.y; s.z += u.z; s.w += u.w;
        }
        float inv = 1.0f / S;
        s.x *= inv; s.y *= inv; s.z *= inv; s.w *= inv;
        reinterpret_cast<float4*>(out)[b * 32 + tid] = s;
    }
}

extern "C" void kernel_launch(void* const* d_in, const int* in_sizes, int n_in,
                              void* d_out, int out_size, void* d_ws, size_t ws_size,
                              hipStream_t stream) {
    const float* x      = (const float*)d_in[0];
    const float* latent = (const float*)d_in[1];
    const float* kern   = (const float*)d_in[2];
    const float* bias   = (const float*)d_in[3];
    const float* beta   = (const float*)d_in[4];
    float* out = (float*)d_out;

    const size_t need = (size_t)B_ * T_ * L_ * sizeof(float);
    if (ws_size >= need) {
        float* ws = (float*)d_ws;
        feat_kernel<<<B_ * T_, 64, 0, stream>>>(x, latent, kern, bias, beta, ws, 0);
        reduce_kernel<<<B_, 256, 0, stream>>>(ws, beta, out);
    } else {
        (void)hipMemsetAsync(d_out, 0, (size_t)out_size * sizeof(float), stream);
        feat_kernel<<<B_ * T_, 64, 0, stream>>>(x, latent, kern, bias, beta, out, 1);
    }
}

// Round 10
// 72.198 us; speedup vs baseline: 1.4107x; 1.3051x over previous
//
#include <hip/hip_runtime.h>
#include <stdint.h>

#define B_ 64
#define T_ 256
#define DF 32
#define L_ 128
#define AW 34      // solve-matrix row stride in floats
#define SLICE 4352 // one token's solve matrix: 32*34*4

typedef float  v2f    __attribute__((ext_vector_type(2)));
typedef float  f32x16 __attribute__((ext_vector_type(16)));
typedef short  bf16x8 __attribute__((ext_vector_type(8)));

// wave-private barrier: drain LDS ops; sched_barrier stops hoisting (rule #18)
#define WAVE_SYNC() do { asm volatile("s_waitcnt lgkmcnt(0)" ::: "memory"); \
                         __builtin_amdgcn_sched_barrier(0); } while (0)

// ds_swizzle with compile-time immediate (builtin requires an ICE argument)
template <int IMM>
__device__ __forceinline__ float swz_f(float v) {
    return __builtin_bit_cast(float, __builtin_amdgcn_ds_swizzle(
        __builtin_bit_cast(int, v), IMM));
}
__device__ __forceinline__ uint32_t cvt_pk_bf16(float a, float b) {
    uint32_t r;
    asm("v_cvt_pk_bf16_f32 %0, %1, %2" : "=v"(r) : "v"(a), "v"(b));
    return r;   // lo16 = bf16(a), hi16 = bf16(b)
}
__device__ __forceinline__ float lo_f(uint32_t p) { return __builtin_bit_cast(float, p << 16); }
__device__ __forceinline__ float hi_f(uint32_t p) { return __builtin_bit_cast(float, p & 0xFFFF0000u); }

struct frag3 { bf16x8 h, m, l; };
union U8 { uint32_t u[4]; bf16x8 v; };

// 3-way bf16 split of 8 f32 values: f = h + m + l, residual ~2^-27
__device__ __forceinline__ frag3 split3(float4 a, float4 b) {
    uint32_t h0 = cvt_pk_bf16(a.x, a.y), h1 = cvt_pk_bf16(a.z, a.w);
    uint32_t h2 = cvt_pk_bf16(b.x, b.y), h3 = cvt_pk_bf16(b.z, b.w);
    float e0 = a.x - lo_f(h0), e1 = a.y - hi_f(h0);
    float e2 = a.z - lo_f(h1), e3 = a.w - hi_f(h1);
    float e4 = b.x - lo_f(h2), e5 = b.y - hi_f(h2);
    float e6 = b.z - lo_f(h3), e7 = b.w - hi_f(h3);
    uint32_t m0 = cvt_pk_bf16(e0, e1), m1 = cvt_pk_bf16(e2, e3);
    uint32_t m2 = cvt_pk_bf16(e4, e5), m3 = cvt_pk_bf16(e6, e7);
    float g0 = e0 - lo_f(m0), g1 = e1 - hi_f(m0);
    float g2 = e2 - lo_f(m1), g3 = e3 - hi_f(m1);
    float g4 = e4 - lo_f(m2), g5 = e5 - hi_f(m2);
    float g6 = e6 - lo_f(m3), g7 = e7 - hi_f(m3);
    uint32_t l0 = cvt_pk_bf16(g0, g1), l1 = cvt_pk_bf16(g2, g3);
    uint32_t l2 = cvt_pk_bf16(g4, g5), l3 = cvt_pk_bf16(g6, g7);
    U8 H, M, L;
    H.u[0] = h0; H.u[1] = h1; H.u[2] = h2; H.u[3] = h3;
    M.u[0] = m0; M.u[1] = m1; M.u[2] = m2; M.u[3] = m3;
    L.u[0] = l0; L.u[1] = l1; L.u[2] = l2; L.u[3] = l3;
    frag3 r; r.h = H.v; r.m = M.v; r.l = L.v; return r;
}

__device__ __forceinline__ f32x16 mfma32(bf16x8 a, bf16x8 b, f32x16 c) {
    return __builtin_amdgcn_mfma_f32_32x32x16_bf16(a, b, c, 0, 0, 0);
}

// ---- merged Gauss-Jordan round K: half g solves token g's system ----
// lane g*32+r holds FULL row r (33 floats) of token g.
// ds_swizzle BitMode (or_mask=K, and_mask=0, xor=0) broadcasts lane K
// within each 32-lane group -> per-half pivot-row broadcast.
template <int K>
__device__ __forceinline__ void gj_round(float (&A)[33], float& dinv, int r) {
    float piv = swz_f<(K << 5)>(A[K]);               // my token's A[K][K]
    float ip = __builtin_amdgcn_rcpf(piv);
    ip = ip * (2.0f - piv * ip);                     // Newton refine
    const bool isk = (r == K);
    float fmul = isk ? 0.f : A[K] * ip;              // my row's col-K value (in reg!)
    dinv = isk ? ip : dinv;
    #pragma unroll
    for (int m = K + 1; m < 33; ++m) {
        float pk = swz_f<(K << 5)>(A[m]);            // row K's col m, my token
        A[m] = fmaf(-fmul, pk, A[m]);
    }
}

template <int K>
struct GJ {
    static __device__ __forceinline__ void run(float (&A)[33], float& dinv, int r) {
        gj_round<K>(A, dinv, r);
        GJ<K + 1>::run(A, dinv, r);
    }
};
template <>
struct GJ<32> {
    static __device__ __forceinline__ void run(float (&)[33], float&, int) {}
};

// One wave (64 threads) per TWO (b,t) tokens: half g owns token g in the solve.
__global__ __launch_bounds__(64) void feat_kernel(
    const float* __restrict__ x,       // [B,T,32]
    const float* __restrict__ latent,  // [B,T,128]
    const float* __restrict__ kern,    // [32,128]
    const float* __restrict__ bias,    // [32,128]
    const float* __restrict__ beta,    // [T]
    float* __restrict__ out,           // mode0: ws[B,T,128] ; mode1: out[B,128]
    int mode)
{
    __shared__ __align__(16) char smem[2 * SLICE];
    const int lane = threadIdx.x;
    const int btA  = blockIdx.x * 2;
    const int btB  = btA + 1;

    const int g = lane >> 5;
    const int r = lane & 31;

    float* AsA = reinterpret_cast<float*>(smem);
    float* AsB = reinterpret_cast<float*>(smem + SLICE);

    const float4* kern4 = reinterpret_cast<const float4*>(kern);
    const float4* bias4 = reinterpret_cast<const float4*>(bias);
    const float4* latA4 = reinterpret_cast<const float4*>(latent) + (size_t)btA * 32;
    const float4* latB4 = reinterpret_cast<const float4*>(latent) + (size_t)btB * 32;

    const float xA = x[(size_t)btA * DF + r];   // x_A[r] in every lane (both halves)
    const float xB = x[(size_t)btB * DF + r];

    f32x16 GA, GB;
    #pragma unroll
    for (int i = 0; i < 16; ++i) { GA[i] = 0.f; GB[i] = 0.f; }
    float ayA = 0.f, ayB = 0.f;

    // ---- 8 k-steps of 16: shared K/B loads, both tokens' frags, 12 MFMA/ks ----
    #pragma unroll 2
    for (int ks = 0; ks < 8; ++ks) {
        const int idx = r * 32 + ks * 4 + g * 2;   // float4 index; k = ks*16 + g*8
        float4 Ka = kern4[idx],  Kb = kern4[idx + 1];
        float4 Ba = bias4[idx],  Bb = bias4[idx + 1];

        float4 faA, fbA, faB, fbB;
        faA.x = fmaxf(fmaf(xA, Ka.x, Ba.x), 0.f);
        faA.y = fmaxf(fmaf(xA, Ka.y, Ba.y), 0.f);
        faA.z = fmaxf(fmaf(xA, Ka.z, Ba.z), 0.f);
        faA.w = fmaxf(fmaf(xA, Ka.w, Ba.w), 0.f);
        fbA.x = fmaxf(fmaf(xA, Kb.x, Bb.x), 0.f);
        fbA.y = fmaxf(fmaf(xA, Kb.y, Bb.y), 0.f);
        fbA.z = fmaxf(fmaf(xA, Kb.z, Bb.z), 0.f);
        fbA.w = fmaxf(fmaf(xA, Kb.w, Bb.w), 0.f);
        faB.x = fmaxf(fmaf(xB, Ka.x, Ba.x), 0.f);
        faB.y = fmaxf(fmaf(xB, Ka.y, Ba.y), 0.f);
        faB.z = fmaxf(fmaf(xB, Ka.z, Ba.z), 0.f);
        faB.w = fmaxf(fmaf(xB, Ka.w, Ba.w), 0.f);
        fbB.x = fmaxf(fmaf(xB, Kb.x, Bb.x), 0.f);
        fbB.y = fmaxf(fmaf(xB, Kb.y, Bb.y), 0.f);
        fbB.z = fmaxf(fmaf(xB, Kb.z, Bb.z), 0.f);
        fbB.w = fmaxf(fmaf(xB, Kb.w, Bb.w), 0.f);

        // xty partials in f32 (exact path)
        float4 laA = latA4[ks * 4 + g * 2], lbA = latA4[ks * 4 + g * 2 + 1];
        float4 laB = latB4[ks * 4 + g * 2], lbB = latB4[ks * 4 + g * 2 + 1];
        ayA = fmaf(faA.x, laA.x, ayA); ayA = fmaf(faA.y, laA.y, ayA);
        ayA = fmaf(faA.z, laA.z, ayA); ayA = fmaf(faA.w, laA.w, ayA);
        ayA = fmaf(fbA.x, lbA.x, ayA); ayA = fmaf(fbA.y, lbA.y, ayA);
        ayA = fmaf(fbA.z, lbA.z, ayA); ayA = fmaf(fbA.w, lbA.w, ayA);
        ayB = fmaf(faB.x, laB.x, ayB); ayB = fmaf(faB.y, laB.y, ayB);
        ayB = fmaf(faB.z, laB.z, ayB); ayB = fmaf(faB.w, laB.w, ayB);
        ayB = fmaf(fbB.x, lbB.x, ayB); ayB = fmaf(fbB.y, lbB.y, ayB);
        ayB = fmaf(fbB.z, lbB.z, ayB); ayB = fmaf(fbB.w, lbB.w, ayB);

        frag3 FA = split3(faA, fbA);
        frag3 FB = split3(faB, fbB);
        GA = mfma32(FA.h, FA.h, GA);
        GB = mfma32(FB.h, FB.h, GB);
        GA = mfma32(FA.h, FA.m, GA);
        GB = mfma32(FB.h, FB.m, GB);
        GA = mfma32(FA.m, FA.h, GA);
        GB = mfma32(FB.m, FB.h, GB);
        GA = mfma32(FA.h, FA.l, GA);
        GB = mfma32(FB.h, FB.l, GB);
        GA = mfma32(FA.l, FA.h, GA);
        GB = mfma32(FB.l, FB.h, GB);
        GA = mfma32(FA.m, FA.m, GA);
        GB = mfma32(FB.m, FB.m, GB);
    }
    ayA += __shfl_xor(ayA, 32);   // full xty_A[r] in every lane
    ayB += __shfl_xor(ayB, 32);

    // ---- spill both Grams + xty into LDS (row-major, m101 C-layout) ----
    #pragma unroll
    for (int reg = 0; reg < 16; ++reg) {
        const int row = (reg & 3) + 8 * (reg >> 2) + 4 * g;
        AsA[row * AW + r] = GA[reg];
        AsB[row * AW + r] = GB[reg];
    }
    if (g == 0) AsA[r * AW + 32] = ayA;
    else        AsB[r * AW + 32] = ayB;
    WAVE_SYNC();

    // ---- reload: lane g*32+r <- FULL row r of token g ----
    float A[33];
    {
        const float* Amy = g ? AsB : AsA;
        #pragma unroll
        for (int m = 0; m < 16; ++m) {
            v2f t = *reinterpret_cast<const v2f*>(&Amy[r * AW + 2 * m]);
            A[2 * m]     = t[0];
            A[2 * m + 1] = t[1];
        }
        A[32] = Amy[r * AW + 32];
    }

    // ---- merged register Gauss-Jordan: both tokens in lockstep, no barriers ----
    float dinv = 0.f;
    GJ<0>::run(A, dinv, r);
    const float s = A[32] * dinv;   // lane g*32+r: solution s_g[r]

    // ---- o_hat both tokens: shared K/Bv loads, f4-col = r, d split across halves ----
    {
        float4 oA = make_float4(0.f, 0.f, 0.f, 0.f);
        float4 oB = make_float4(0.f, 0.f, 0.f, 0.f);
        #pragma unroll
        for (int dd = 0; dd < 16; ++dd) {
            int d = g * 16 + dd;
            float4 K  = kern4[d * 32 + r];
            float4 Bv = bias4[d * 32 + r];
            float xvA = __shfl(xA, d);        // x_A[d]
            float xvB = __shfl(xB, d);
            float sA  = __shfl(s, d);         // s_A[d] (from half 0)
            float sB  = __shfl(s, 32 + d);    // s_B[d] (from half 1)
            float fx = fmaxf(fmaf(xvA, K.x, Bv.x), 0.f);
            float fy = fmaxf(fmaf(xvA, K.y, Bv.y), 0.f);
            float fz = fmaxf(fmaf(xvA, K.z, Bv.z), 0.f);
            float fw = fmaxf(fmaf(xvA, K.w, Bv.w), 0.f);
            oA.x = fmaf(sA, fx, oA.x);
            oA.y = fmaf(sA, fy, oA.y);
            oA.z = fmaf(sA, fz, oA.z);
            oA.w = fmaf(sA, fw, oA.w);
            fx = fmaxf(fmaf(xvB, K.x, Bv.x), 0.f);
            fy = fmaxf(fmaf(xvB, K.y, Bv.y), 0.f);
            fz = fmaxf(fmaf(xvB, K.z, Bv.z), 0.f);
            fw = fmaxf(fmaf(xvB, K.w, Bv.w), 0.f);
            oB.x = fmaf(sB, fx, oB.x);
            oB.y = fmaf(sB, fy, oB.y);
            oB.z = fmaf(sB, fz, oB.z);
            oB.w = fmaf(sB, fw, oB.w);
        }
        oA.x += __shfl_xor(oA.x, 32); oA.y += __shfl_xor(oA.y, 32);
        oA.z += __shfl_xor(oA.z, 32); oA.w += __shfl_xor(oA.w, 32);
        oB.x += __shfl_xor(oB.x, 32); oB.y += __shfl_xor(oB.y, 32);
        oB.z += __shfl_xor(oB.z, 32); oB.w += __shfl_xor(oB.w, 32);

        if (mode == 0) {
            if (g == 0) reinterpret_cast<float4*>(out)[(size_t)btA * 32 + r] = oA;
            else        reinterpret_cast<float4*>(out)[(size_t)btB * 32 + r] = oB;
        } else {
            float v = fabsf(beta[lane]) + fabsf(beta[lane + 64]) +
                      fabsf(beta[lane + 128]) + fabsf(beta[lane + 192]);
            #pragma unroll
            for (int off = 32; off > 0; off >>= 1) v += __shfl_down(v, off);
            float S = __shfl(v, 0);
            const int tA = btA & (T_ - 1), tB = btB & (T_ - 1);
            const int b  = btA >> 8;
            if (g == 0) {
                float w_t = fabsf(beta[tA]) / S;
                float* op = &out[(size_t)b * L_ + 4 * r];
                atomicAdd(op + 0, oA.x * w_t);
                atomicAdd(op + 1, oA.y * w_t);
                atomicAdd(op + 2, oA.z * w_t);
                atomicAdd(op + 3, oA.w * w_t);
            } else {
                float w_t = fabsf(beta[tB]) / S;
                float* op = &out[(size_t)b * L_ + 4 * r];
                atomicAdd(op + 0, oB.x * w_t);
                atomicAdd(op + 1, oB.y * w_t);
                atomicAdd(op + 2, oB.z * w_t);
                atomicAdd(op + 3, oB.w * w_t);
            }
        }
    }
}

__global__ __launch_bounds__(256) void reduce_kernel(
    const float* __restrict__ ws,     // [B,T,128] o_hat (unscaled)
    const float* __restrict__ beta,   // [T]
    float* __restrict__ out)          // [B,128]
{
    __shared__ float wsh[T_];
    __shared__ __align__(16) float4 par[8][32];
    __shared__ float red[4];
    const int b = blockIdx.x, tid = threadIdx.x;

    float bv = fabsf(beta[tid]);
    wsh[tid] = bv;
    float v = bv;
    #pragma unroll
    for (int o = 32; o > 0; o >>= 1) v += __shfl_down(v, o);
    if ((tid & 63) == 0) red[tid >> 6] = v;
    __syncthreads();
    const float S = red[0] + red[1] + red[2] + red[3];

    const int c = tid & 31, gg = tid >> 5;
    const float4* ws4 = reinterpret_cast<const float4*>(ws);
    float4 a = make_float4(0.f, 0.f, 0.f, 0.f);
    #pragma unroll 4
    for (int tt = 0; tt < 32; ++tt) {
        int t = gg * 32 + tt;
        float w = wsh[t];
        float4 u = ws4[((size_t)b * T_ + t) * 32 + c];
        a.x = fmaf(u.x, w, a.x);
        a.y = fmaf(u.y, w, a.y);
        a.z = fmaf(u.z, w, a.z);
        a.w = fmaf(u.w, w, a.w);
    }
    par[gg][c] = a;
    __syncthreads();
    if (tid < 32) {
        float4 s = par[0][tid];
        #pragma unroll
        for (int p = 1; p < 8; ++p) {
            float4 u = par[p][tid];
            s.x += u.x; s.y += u.y; s.z += u.z; s.w += u.w;
        }
        float inv = 1.0f / S;
        s.x *= inv; s.y *= inv; s.z *= inv; s.w *= inv;
        reinterpret_cast<float4*>(out)[b * 32 + tid] = s;
    }
}

extern "C" void kernel_launch(void* const* d_in, const int* in_sizes, int n_in,
                              void* d_out, int out_size, void* d_ws, size_t ws_size,
                              hipStream_t stream) {
    const float* x      = (const float*)d_in[0];
    const float* latent = (const float*)d_in[1];
    const float* kern   = (const float*)d_in[2];
    const float* bias   = (const float*)d_in[3];
    const float* beta   = (const float*)d_in[4];
    float* out = (float*)d_out;

    const size_t need = (size_t)B_ * T_ * L_ * sizeof(float);
    if (ws_size >= need) {
        float* ws = (float*)d_ws;
        feat_kernel<<<(B_ * T_) / 2, 64, 0, stream>>>(x, latent, kern, bias, beta, ws, 0);
        reduce_kernel<<<B_, 256, 0, stream>>>(ws, beta, out);
    } else {
        (void)hipMemsetAsync(d_out, 0, (size_t)out_size * sizeof(float), stream);
        feat_kernel<<<(B_ * T_) / 2, 64, 0, stream>>>(x, latent, kern, bias, beta, out, 1);
    }
}

// Round 11
// 71.683 us; speedup vs baseline: 1.4208x; 1.0072x over previous
//
#include <hip/hip_runtime.h>
#include <stdint.h>

#define B_ 64
#define T_ 256
#define DF 32
#define L_ 128
#define AW 34      // solve-matrix row stride in floats
#define SLICE 4352 // one token's solve matrix: 32*34*4

typedef float  v2f    __attribute__((ext_vector_type(2)));
typedef float  f32x16 __attribute__((ext_vector_type(16)));
typedef short  bf16x8 __attribute__((ext_vector_type(8)));

// wave-private barrier: drain LDS ops; sched_barrier stops hoisting (rule #18)
#define WAVE_SYNC() do { asm volatile("s_waitcnt lgkmcnt(0)" ::: "memory"); \
                         __builtin_amdgcn_sched_barrier(0); } while (0)

// ds_swizzle with compile-time immediate (builtin requires an ICE argument)
template <int IMM>
__device__ __forceinline__ float swz_f(float v) {
    return __builtin_bit_cast(float, __builtin_amdgcn_ds_swizzle(
        __builtin_bit_cast(int, v), IMM));
}
__device__ __forceinline__ uint32_t cvt_pk_bf16(float a, float b) {
    uint32_t r;
    asm("v_cvt_pk_bf16_f32 %0, %1, %2" : "=v"(r) : "v"(a), "v"(b));
    return r;   // lo16 = bf16(a), hi16 = bf16(b)
}
__device__ __forceinline__ float lo_f(uint32_t p) { return __builtin_bit_cast(float, p << 16); }
__device__ __forceinline__ float hi_f(uint32_t p) { return __builtin_bit_cast(float, p & 0xFFFF0000u); }

struct frag3 { bf16x8 h, m, l; };
union U8 { uint32_t u[4]; bf16x8 v; };

// 3-way bf16 split of 8 f32 values: f = h + m + l, residual ~2^-27
__device__ __forceinline__ frag3 split3(float4 a, float4 b) {
    uint32_t h0 = cvt_pk_bf16(a.x, a.y), h1 = cvt_pk_bf16(a.z, a.w);
    uint32_t h2 = cvt_pk_bf16(b.x, b.y), h3 = cvt_pk_bf16(b.z, b.w);
    float e0 = a.x - lo_f(h0), e1 = a.y - hi_f(h0);
    float e2 = a.z - lo_f(h1), e3 = a.w - hi_f(h1);
    float e4 = b.x - lo_f(h2), e5 = b.y - hi_f(h2);
    float e6 = b.z - lo_f(h3), e7 = b.w - hi_f(h3);
    uint32_t m0 = cvt_pk_bf16(e0, e1), m1 = cvt_pk_bf16(e2, e3);
    uint32_t m2 = cvt_pk_bf16(e4, e5), m3 = cvt_pk_bf16(e6, e7);
    float g0 = e0 - lo_f(m0), g1 = e1 - hi_f(m0);
    float g2 = e2 - lo_f(m1), g3 = e3 - hi_f(m1);
    float g4 = e4 - lo_f(m2), g5 = e5 - hi_f(m2);
    float g6 = e6 - lo_f(m3), g7 = e7 - hi_f(m3);
    uint32_t l0 = cvt_pk_bf16(g0, g1), l1 = cvt_pk_bf16(g2, g3);
    uint32_t l2 = cvt_pk_bf16(g4, g5), l3 = cvt_pk_bf16(g6, g7);
    U8 H, M, L;
    H.u[0] = h0; H.u[1] = h1; H.u[2] = h2; H.u[3] = h3;
    M.u[0] = m0; M.u[1] = m1; M.u[2] = m2; M.u[3] = m3;
    L.u[0] = l0; L.u[1] = l1; L.u[2] = l2; L.u[3] = l3;
    frag3 r; r.h = H.v; r.m = M.v; r.l = L.v; return r;
}

__device__ __forceinline__ f32x16 mfma32(bf16x8 a, bf16x8 b, f32x16 c) {
    return __builtin_amdgcn_mfma_f32_32x32x16_bf16(a, b, c, 0, 0, 0);
}

// ---- merged Gauss-Jordan round K: half g solves token g's system ----
// lane g*32+r holds FULL row r (33 floats) of token g.
// ds_swizzle BitMode (or_mask=K) broadcasts lane K within each 32-lane group.
template <int K>
__device__ __forceinline__ void gj_round(float (&A)[33], float& dinv, int r) {
    float piv = swz_f<(K << 5)>(A[K]);               // my token's A[K][K]
    float ip = __builtin_amdgcn_rcpf(piv);           // ~1 ulp native rcp
    const bool isk = (r == K);
    float fmul = isk ? 0.f : A[K] * ip;              // my row's col-K value (in reg)
    dinv = isk ? ip : dinv;                          // capture my diagonal reciprocal
    #pragma unroll
    for (int m = K + 1; m < 33; ++m) {
        float pk = swz_f<(K << 5)>(A[m]);            // row K's col m, my token
        A[m] = fmaf(-fmul, pk, A[m]);
    }
}

template <int K>
struct GJ {
    static __device__ __forceinline__ void run(float (&A)[33], float& dinv, int r) {
        gj_round<K>(A, dinv, r);
        GJ<K + 1>::run(A, dinv, r);
    }
};
template <>
struct GJ<32> {
    static __device__ __forceinline__ void run(float (&)[33], float&, int) {}
};

// 128-thread blocks = 2 independent waves; each wave owns TWO (b,t) tokens.
__global__ __launch_bounds__(128) void feat_kernel(
    const float* __restrict__ x,       // [B,T,32]
    const float* __restrict__ latent,  // [B,T,128]
    const float* __restrict__ kern,    // [32,128]
    const float* __restrict__ bias,    // [32,128]
    const float* __restrict__ beta,    // [T]
    float* __restrict__ out,           // mode0: ws[B,T,128] ; mode1: out[B,128]
    int mode)
{
    __shared__ __align__(16) char smem[4 * SLICE];
    const int tid  = threadIdx.x;
    const int wid  = tid >> 6;         // wave within block (0/1)
    const int lane = tid & 63;
    const int btA  = blockIdx.x * 4 + wid * 2;
    const int btB  = btA + 1;

    const int g = lane >> 5;
    const int r = lane & 31;

    float* AsA = reinterpret_cast<float*>(smem + wid * 2 * SLICE);
    float* AsB = reinterpret_cast<float*>(smem + wid * 2 * SLICE + SLICE);

    const float4* kern4 = reinterpret_cast<const float4*>(kern);
    const float4* bias4 = reinterpret_cast<const float4*>(bias);
    const float4* latA4 = reinterpret_cast<const float4*>(latent) + (size_t)btA * 32;
    const float4* latB4 = reinterpret_cast<const float4*>(latent) + (size_t)btB * 32;

    const float xA = x[(size_t)btA * DF + r];   // x_A[r] in every lane (both halves)
    const float xB = x[(size_t)btB * DF + r];

    f32x16 GA, GB;
    #pragma unroll
    for (int i = 0; i < 16; ++i) { GA[i] = 0.f; GB[i] = 0.f; }
    float ayA = 0.f, ayB = 0.f;

    // ---- 8 k-steps of 16: shared K/B loads, both tokens' frags, 12 MFMA/ks ----
    #pragma unroll 2
    for (int ks = 0; ks < 8; ++ks) {
        const int idx = r * 32 + ks * 4 + g * 2;   // float4 index; k = ks*16 + g*8
        float4 Ka = kern4[idx],  Kb = kern4[idx + 1];
        float4 Ba = bias4[idx],  Bb = bias4[idx + 1];

        float4 faA, fbA, faB, fbB;
        faA.x = fmaxf(fmaf(xA, Ka.x, Ba.x), 0.f);
        faA.y = fmaxf(fmaf(xA, Ka.y, Ba.y), 0.f);
        faA.z = fmaxf(fmaf(xA, Ka.z, Ba.z), 0.f);
        faA.w = fmaxf(fmaf(xA, Ka.w, Ba.w), 0.f);
        fbA.x = fmaxf(fmaf(xA, Kb.x, Bb.x), 0.f);
        fbA.y = fmaxf(fmaf(xA, Kb.y, Bb.y), 0.f);
        fbA.z = fmaxf(fmaf(xA, Kb.z, Bb.z), 0.f);
        fbA.w = fmaxf(fmaf(xA, Kb.w, Bb.w), 0.f);
        faB.x = fmaxf(fmaf(xB, Ka.x, Ba.x), 0.f);
        faB.y = fmaxf(fmaf(xB, Ka.y, Ba.y), 0.f);
        faB.z = fmaxf(fmaf(xB, Ka.z, Ba.z), 0.f);
        faB.w = fmaxf(fmaf(xB, Ka.w, Ba.w), 0.f);
        fbB.x = fmaxf(fmaf(xB, Kb.x, Bb.x), 0.f);
        fbB.y = fmaxf(fmaf(xB, Kb.y, Bb.y), 0.f);
        fbB.z = fmaxf(fmaf(xB, Kb.z, Bb.z), 0.f);
        fbB.w = fmaxf(fmaf(xB, Kb.w, Bb.w), 0.f);

        // xty partials in f32 (exact path)
        float4 laA = latA4[ks * 4 + g * 2], lbA = latA4[ks * 4 + g * 2 + 1];
        float4 laB = latB4[ks * 4 + g * 2], lbB = latB4[ks * 4 + g * 2 + 1];
        ayA = fmaf(faA.x, laA.x, ayA); ayA = fmaf(faA.y, laA.y, ayA);
        ayA = fmaf(faA.z, laA.z, ayA); ayA = fmaf(faA.w, laA.w, ayA);
        ayA = fmaf(fbA.x, lbA.x, ayA); ayA = fmaf(fbA.y, lbA.y, ayA);
        ayA = fmaf(fbA.z, lbA.z, ayA); ayA = fmaf(fbA.w, lbA.w, ayA);
        ayB = fmaf(faB.x, laB.x, ayB); ayB = fmaf(faB.y, laB.y, ayB);
        ayB = fmaf(faB.z, laB.z, ayB); ayB = fmaf(faB.w, laB.w, ayB);
        ayB = fmaf(fbB.x, lbB.x, ayB); ayB = fmaf(fbB.y, lbB.y, ayB);
        ayB = fmaf(fbB.z, lbB.z, ayB); ayB = fmaf(fbB.w, lbB.w, ayB);

        frag3 FA = split3(faA, fbA);
        frag3 FB = split3(faB, fbB);
        GA = mfma32(FA.h, FA.h, GA);
        GB = mfma32(FB.h, FB.h, GB);
        GA = mfma32(FA.h, FA.m, GA);
        GB = mfma32(FB.h, FB.m, GB);
        GA = mfma32(FA.m, FA.h, GA);
        GB = mfma32(FB.m, FB.h, GB);
        GA = mfma32(FA.h, FA.l, GA);
        GB = mfma32(FB.h, FB.l, GB);
        GA = mfma32(FA.l, FA.h, GA);
        GB = mfma32(FB.l, FB.h, GB);
        GA = mfma32(FA.m, FA.m, GA);
        GB = mfma32(FB.m, FB.m, GB);
    }
    ayA += __shfl_xor(ayA, 32);   // full xty_A[r] in every lane
    ayB += __shfl_xor(ayB, 32);

    // ---- spill both Grams + xty into LDS (row-major, m101 C-layout) ----
    #pragma unroll
    for (int reg = 0; reg < 16; ++reg) {
        const int row = (reg & 3) + 8 * (reg >> 2) + 4 * g;
        AsA[row * AW + r] = GA[reg];
        AsB[row * AW + r] = GB[reg];
    }
    if (g == 0) AsA[r * AW + 32] = ayA;
    else        AsB[r * AW + 32] = ayB;
    WAVE_SYNC();

    // ---- reload: lane g*32+r <- FULL row r of token g ----
    float A[33];
    {
        const float* Amy = g ? AsB : AsA;
        #pragma unroll
        for (int m = 0; m < 16; ++m) {
            v2f t = *reinterpret_cast<const v2f*>(&Amy[r * AW + 2 * m]);
            A[2 * m]     = t[0];
            A[2 * m + 1] = t[1];
        }
        A[32] = Amy[r * AW + 32];
    }

    // ---- merged register Gauss-Jordan: both tokens in lockstep, no barriers ----
    float dinv = 0.f;
    GJ<0>::run(A, dinv, r);
    const float s = A[32] * dinv;   // lane g*32+r: solution s_g[r]

    // ---- o_hat both tokens: shared K/Bv loads, f4-col = r, d split across halves ----
    {
        float4 oA = make_float4(0.f, 0.f, 0.f, 0.f);
        float4 oB = make_float4(0.f, 0.f, 0.f, 0.f);
        #pragma unroll
        for (int dd = 0; dd < 16; ++dd) {
            int d = g * 16 + dd;
            float4 K  = kern4[d * 32 + r];
            float4 Bv = bias4[d * 32 + r];
            float xvA = __shfl(xA, d);        // x_A[d]
            float xvB = __shfl(xB, d);
            float sA  = __shfl(s, d);         // s_A[d] (from half 0)
            float sB  = __shfl(s, 32 + d);    // s_B[d] (from half 1)
            float fx = fmaxf(fmaf(xvA, K.x, Bv.x), 0.f);
            float fy = fmaxf(fmaf(xvA, K.y, Bv.y), 0.f);
            float fz = fmaxf(fmaf(xvA, K.z, Bv.z), 0.f);
            float fw = fmaxf(fmaf(xvA, K.w, Bv.w), 0.f);
            oA.x = fmaf(sA, fx, oA.x);
            oA.y = fmaf(sA, fy, oA.y);
            oA.z = fmaf(sA, fz, oA.z);
            oA.w = fmaf(sA, fw, oA.w);
            fx = fmaxf(fmaf(xvB, K.x, Bv.x), 0.f);
            fy = fmaxf(fmaf(xvB, K.y, Bv.y), 0.f);
            fz = fmaxf(fmaf(xvB, K.z, Bv.z), 0.f);
            fw = fmaxf(fmaf(xvB, K.w, Bv.w), 0.f);
            oB.x = fmaf(sB, fx, oB.x);
            oB.y = fmaf(sB, fy, oB.y);
            oB.z = fmaf(sB, fz, oB.z);
            oB.w = fmaf(sB, fw, oB.w);
        }
        oA.x += __shfl_xor(oA.x, 32); oA.y += __shfl_xor(oA.y, 32);
        oA.z += __shfl_xor(oA.z, 32); oA.w += __shfl_xor(oA.w, 32);
        oB.x += __shfl_xor(oB.x, 32); oB.y += __shfl_xor(oB.y, 32);
        oB.z += __shfl_xor(oB.z, 32); oB.w += __shfl_xor(oB.w, 32);

        if (mode == 0) {
            if (g == 0) reinterpret_cast<float4*>(out)[(size_t)btA * 32 + r] = oA;
            else        reinterpret_cast<float4*>(out)[(size_t)btB * 32 + r] = oB;
        } else {
            float v = fabsf(beta[lane]) + fabsf(beta[lane + 64]) +
                      fabsf(beta[lane + 128]) + fabsf(beta[lane + 192]);
            #pragma unroll
            for (int off = 32; off > 0; off >>= 1) v += __shfl_down(v, off);
            float S = __shfl(v, 0);
            const int tA = btA & (T_ - 1), tB = btB & (T_ - 1);
            const int b  = btA >> 8;
            if (g == 0) {
                float w_t = fabsf(beta[tA]) / S;
                float* op = &out[(size_t)b * L_ + 4 * r];
                atomicAdd(op + 0, oA.x * w_t);
                atomicAdd(op + 1, oA.y * w_t);
                atomicAdd(op + 2, oA.z * w_t);
                atomicAdd(op + 3, oA.w * w_t);
            } else {
                float w_t = fabsf(beta[tB]) / S;
                float* op = &out[(size_t)b * L_ + 4 * r];
                atomicAdd(op + 0, oB.x * w_t);
                atomicAdd(op + 1, oB.y * w_t);
                atomicAdd(op + 2, oB.z * w_t);
                atomicAdd(op + 3, oB.w * w_t);
            }
        }
    }
}

__global__ __launch_bounds__(256) void reduce_kernel(
    const float* __restrict__ ws,     // [B,T,128] o_hat (unscaled)
    const float* __restrict__ beta,   // [T]
    float* __restrict__ out)          // [B,128]
{
    __shared__ float wsh[T_];
    __shared__ __align__(16) float4 par[8][32];
    __shared__ float red[4];
    const int b = blockIdx.x, tid = threadIdx.x;

    float bv = fabsf(beta[tid]);
    wsh[tid] = bv;
    float v = bv;
    #pragma unroll
    for (int o = 32; o > 0; o >>= 1) v += __shfl_down(v, o);
    if ((tid & 63) == 0) red[tid >> 6] = v;
    __syncthreads();
    const float S = red[0] + red[1] + red[2] + red[3];

    const int c = tid & 31, gg = tid >> 5;
    const float4* ws4 = reinterpret_cast<const float4*>(ws);
    float4 a = make_float4(0.f, 0.f, 0.f, 0.f);
    #pragma unroll 4
    for (int tt = 0; tt < 32; ++tt) {
        int t = gg * 32 + tt;
        float w = wsh[t];
        float4 u = ws4[((size_t)b * T_ + t) * 32 + c];
        a.x = fmaf(u.x, w, a.x);
        a.y = fmaf(u.y, w, a.y);
        a.z = fmaf(u.z, w, a.z);
        a.w = fmaf(u.w, w, a.w);
    }
    par[gg][c] = a;
    __syncthreads();
    if (tid < 32) {
        float4 s = par[0][tid];
        #pragma unroll
        for (int p = 1; p < 8; ++p) {
            float4 u = par[p][tid];
            s.x += u.x; s.y += u.y; s.z += u.z; s.w += u.w;
        }
        float inv = 1.0f / S;
        s.x *= inv; s.y *= inv; s.z *= inv; s.w *= inv;
        reinterpret_cast<float4*>(out)[b * 32 + tid] = s;
    }
}

extern "C" void kernel_launch(void* const* d_in, const int* in_sizes, int n_in,
                              void* d_out, int out_size, void* d_ws, size_t ws_size,
                              hipStream_t stream) {
    const float* x      = (const float*)d_in[0];
    const float* latent = (const float*)d_in[1];
    const float* kern   = (const float*)d_in[2];
    const float* bias   = (const float*)d_in[3];
    const float* beta   = (const float*)d_in[4];
    float* out = (float*)d_out;

    const size_t need = (size_t)B_ * T_ * L_ * sizeof(float);
    if (ws_size >= need) {
        float* ws = (float*)d_ws;
        feat_kernel<<<(B_ * T_) / 4, 128, 0, stream>>>(x, latent, kern, bias, beta, ws, 0);
        reduce_kernel<<<B_, 256, 0, stream>>>(ws, beta, out);
    } else {
        (void)hipMemsetAsync(d_out, 0, (size_t)out_size * sizeof(float), stream);
        feat_kernel<<<(B_ * T_) / 4, 128, 0, stream>>>(x, latent, kern, bias, beta, out, 1);
    }
}